// Round 7
// baseline (70.678 us; speedup 1.0000x reference)
//
#include <hip/hip_runtime.h>
#include <math.h>

#define S 256
#define H 1024
#define NTAG 20
#define NPAIR 32640  // S*(S-1)/2

typedef short s16x8 __attribute__((ext_vector_type(8)));
typedef float f32x4 __attribute__((ext_vector_type(4)));

// ---- workspace layout (float indices) ----
#define WS_HBF   0        // h as bf16 [256][1024] ushort (=131072 floats)
#define WS_W1T   131072   // w1 transposed bf16 [1024 c][1024 k] ushort (=524288 floats)
#define WS_APART 655360   // [64 cg][256 s] score partials
#define WS_HP    671744   // [8 kc][3 p][256 s][20 t] hw partials
#define WS_A     794624   // [256]
#define WS_ZC    794880   // [257]
#define WS_HW0   795140   // [256*20]
#define WS_HW1   800260   // [256*20]
#define WS_HW2   805380   // [256*20]
#define WS_PW    810500   // [257*20]
#define WS_LW    815640   // [257*20]
#define WS_LOSSP 820780   // [255]
#define WS_RUN   821036   // int[256]
#define WS_START 821292   // int[256]
#define WS_END   821548   // int[256]
#define WS_CTR   821804   // int ticket (K3)
#define WS_CTR2  821805   // int ticket (K4)

__device__ __forceinline__ unsigned short f2bf(float x) {
    unsigned int u = __float_as_uint(x);
    unsigned int r = u + 0x7FFFu + ((u >> 16) & 1u);   // RNE
    return (unsigned short)(r >> 16);
}

__device__ __forceinline__ float tanh_fast(float x) {
    const float xc = fminf(fmaxf(x, -15.f), 15.f);
    const float ex = __expf(2.f * xc);
    return (ex - 1.f) / (ex + 1.f);
}

// ============ K1: bf16 conversions + hw partials + ticket zero ============
// b<64: h->bf16. 64<=b<320: w1 -> w1T bf16 (64x64 LDS tile transpose).
// b>=320: hw partials (R3-verified path).
__global__ __launch_bounds__(256) void K1(const float* __restrict__ hidden,
                                          const float* __restrict__ w1,
                                          const float* __restrict__ fcw,
                                          float* __restrict__ ws) {
    const int tid = threadIdx.x;
    const int b = blockIdx.x;
    __shared__ float tile[64][65];
    __shared__ __align__(16) float shHT[128][20];

    if (b == 0 && tid == 0) {
        ((int*)ws)[WS_CTR] = 0;
        ((int*)ws)[WS_CTR2] = 0;
    }

    if (b < 64) {
        unsigned short* hb = (unsigned short*)(ws + WS_HBF);
        #pragma unroll
        for (int e = 0; e < 16; e++) {
            const int idx = e * 16384 + b * 256 + tid;
            hb[idx] = f2bf(hidden[idx]);
        }
    } else if (b < 320) {
        const int tb = b - 64;
        const int r0 = (tb & 15) * 64, c0 = (tb >> 4) * 64;
        unsigned short* wt = (unsigned short*)(ws + WS_W1T);
        #pragma unroll
        for (int e = 0; e < 16; e++) {
            const int rr = e * 4 + (tid >> 6);
            tile[rr][tid & 63] = w1[(size_t)(r0 + rr) * H + c0 + (tid & 63)];
        }
        __syncthreads();
        #pragma unroll
        for (int e = 0; e < 16; e++) {
            const int cr = e * 4 + (tid >> 6);
            wt[(size_t)(c0 + cr) * H + r0 + (tid & 63)] = f2bf(tile[tid & 63][cr]);
        }
    } else {
        const int hb2 = b - 320;
        const int rg = hb2 & 15, kc = hb2 >> 4;
        {
            const int c = tid & 127, rr = tid >> 7;
            #pragma unroll
            for (int e = 0; e < 8; e++) {
                const int r = e * 2 + rr;
                shHT[c][r] = hidden[(rg * 16 + r) * H + kc * 128 + c];
            }
        }
        __syncthreads();
        if (tid < 240) {
            const int t = tid % 20, g = tid / 20;   // g 0..11
            const int p = g >> 2, rsub = g & 3;
            const float* fw = fcw + (size_t)(p * H + kc * 128) * 20 + t;
            float a0 = 0.f, a1 = 0.f, a2 = 0.f, a3 = 0.f;
            #pragma unroll 8
            for (int k = 0; k < 128; k++) {
                const float w = fw[k * 20];
                const float4 h4 = *(const float4*)&shHT[k][rsub * 4];
                a0 = fmaf(h4.x, w, a0);
                a1 = fmaf(h4.y, w, a1);
                a2 = fmaf(h4.z, w, a2);
                a3 = fmaf(h4.w, w, a3);
            }
            float* hpo = ws + WS_HP + ((size_t)(kc * 3 + p) * 256 + rg * 16 + rsub * 4) * 20 + t;
            hpo[0] = a0; hpo[20] = a1; hpo[40] = a2; hpo[60] = a3;
        }
    }
}

// ============ K2: MFMA score GEMM + fused tanh/w2 epilogue ============
// 256 blocks x 256 thr (4 waves). Block: rows (b&15)*16..+15, cols (b>>4)*64..+63.
// Wave w: 16x16 tile at c0=(b>>4)*64+w*16, full K=1024 (32 mfma).
// A-frag: lane holds h_bf[r0+(lane&15)][quad*8..+7] (contiguous 16B).
// B-frag: lane holds w1T[c0+(lane&15)][quad*8..+7].
// D: col=lane&15 (c), row=quad*4+reg (m89-verified).
__global__ __launch_bounds__(256) void K2(const float* __restrict__ b1,
                                          const float* __restrict__ w2,
                                          float* __restrict__ ws) {
    const int tid = threadIdx.x;
    const int b = blockIdx.x;
    const int lane = tid & 63, w = tid >> 6;
    const int r0 = (b & 15) * 16;
    const int cgB = b >> 4;
    const int c0 = cgB * 64 + w * 16;
    const int fr = lane & 15, quad = lane >> 4;

    const unsigned short* hb = (const unsigned short*)(ws + WS_HBF);
    const unsigned short* wt = (const unsigned short*)(ws + WS_W1T);
    const unsigned short* ap = hb + (size_t)(r0 + fr) * H + quad * 8;
    const unsigned short* bp = wt + (size_t)(c0 + fr) * H + quad * 8;

    f32x4 acc = {0.f, 0.f, 0.f, 0.f};
    #pragma unroll 8
    for (int kb = 0; kb < 32; kb++) {
        const s16x8 aF = *(const s16x8*)(ap + kb * 32);
        const s16x8 bF = *(const s16x8*)(bp + kb * 32);
        acc = __builtin_amdgcn_mfma_f32_16x16x32_bf16(aF, bF, acc, 0, 0, 0);
    }

    const float b1v = b1[c0 + fr];
    const float w2v = w2[c0 + fr];
    const int cg64 = cgB * 4 + w;
    #pragma unroll
    for (int reg = 0; reg < 4; reg++) {
        float t = tanh_fast(acc[reg] + b1v) * w2v;
        t += __shfl_xor(t, 1, 16);
        t += __shfl_xor(t, 2, 16);
        t += __shfl_xor(t, 4, 16);
        t += __shfl_xor(t, 8, 16);
        if (fr == 0)
            ws[WS_APART + cg64 * 256 + r0 + quad * 4 + reg] = t;
    }
}

// ============ K3: a 64-way sum + hw 8-way reduce; last block: all scans ============
__global__ __launch_bounds__(256) void K3(const float* __restrict__ b2,
                                          const int* __restrict__ target,
                                          const float* __restrict__ lenemb,
                                          const float* __restrict__ fcw,
                                          float* __restrict__ ws) {
    const int b = blockIdx.x, tid = threadIdx.x;
    __shared__ float sred[256];
    __shared__ int sticket;

    sred[tid] = (tid < 64) ? ws[WS_APART + tid * 256 + b] : 0.f;
    __syncthreads();
    for (int off = 128; off > 0; off >>= 1) {
        if (tid < off) sred[tid] += sred[tid + off];
        __syncthreads();
    }
    if (tid == 0) ws[WS_A + b] = sred[0];

    if (tid < 60) {
        const int t = tid % 20, p = tid / 20;
        float s = 0.f;
        #pragma unroll
        for (int kc = 0; kc < 8; kc++)
            s += ws[WS_HP + ((size_t)(kc * 3 + p) * 256 + b) * 20 + t];
        const int base = (p == 0) ? WS_HW0 : (p == 1) ? WS_HW1 : WS_HW2;
        ws[base + b * 20 + t] = s;
    }

    __threadfence();
    __syncthreads();
    if (tid == 0) sticket = atomicAdd((int*)ws + WS_CTR, 1);
    __syncthreads();
    if (sticket != 255) return;
    __threadfence();

    {
        const int s = tid;
        __shared__ float shf[256], she[256];
        __shared__ int shi[256], shtg[256];
        __shared__ float shlen[2550];
        __shared__ float shfct[200];
        __shared__ float shw0[5120];
        __shared__ float shpw[5120];
        __shared__ float soff[4][20];

        for (int idx = s; idx < 2550; idx += 256) shlen[idx] = lenemb[20 + idx];
        if (s < 200) shfct[s] = fcw[61440 + s];
        for (int idx = s; idx < 5120; idx += 256) shw0[idx] = ws[WS_HW0 + idx];

        shtg[s] = target[s];
        const float a = ws[WS_A + s] + b2[0];
        shf[s] = a;
        __syncthreads();

        for (int item = s; item < 5100; item += 256) {
            const int L2i = item / 20, t = item % 20;   // L = L2i + 2
            float v = 0.f;
            #pragma unroll
            for (int d = 0; d < 10; d++)
                v = fmaf(shlen[L2i * 10 + d], shfct[d * 20 + t], v);
            ws[WS_LW + (L2i + 2) * 20 + t] = v;
        }

        for (int off = 128; off > 0; off >>= 1) {
            if (s < off) shf[s] = fmaxf(shf[s], shf[s + off]);
            __syncthreads();
        }
        const float mx = shf[0];
        __syncthreads();
        const float ev = __expf(a - mx);
        she[s] = ev;
        shf[s] = ev;
        const int chg = (s == 0) ? 1 : (shtg[s] != shtg[s - 1]);
        shi[s] = chg;
        __syncthreads();
        for (int off = 1; off < 256; off <<= 1) {
            const float fv = (s >= off) ? shf[s - off] : 0.f;
            const int   iv = (s >= off) ? shi[s - off] : 0;
            __syncthreads();
            shf[s] += fv;
            shi[s] += iv;
            __syncthreads();
        }
        ws[WS_ZC + s + 1] = shf[s];
        if (s == 0) ws[WS_ZC] = 0.f;
        ((int*)ws)[WS_RUN + s]   = shi[s];
        ((int*)ws)[WS_START + s] = chg;
        ((int*)ws)[WS_END + s]   = (s == 255) ? 1 : (shtg[s] != shtg[s + 1]);

        if (s < 80) {
            const int t = s % 20, seg = s / 20;
            const int base = seg * 64;
            float pw = 0.f;
            for (int k = 0; k < 64; k++) {
                pw = fmaf(she[base + k], shw0[(base + k) * 20 + t], pw);
                shpw[(base + k) * 20 + t] = pw;
            }
        }
        __syncthreads();
        if (s < 20) {
            const float T0 = shpw[63 * 20 + s], T1 = shpw[127 * 20 + s], T2 = shpw[191 * 20 + s];
            soff[0][s] = 0.f; soff[1][s] = T0; soff[2][s] = T0 + T1; soff[3][s] = T0 + T1 + T2;
        }
        __syncthreads();
        for (int item = s; item < 5140; item += 256) {
            const int r = item / 20, t = item % 20;
            const float v = (r == 0) ? 0.f : shpw[(r - 1) * 20 + t] + soff[(r - 1) >> 6][t];
            ws[WS_PW + item] = v;
        }
    }
}

// ============ K4: pairs (255 x 128 = 32640) + last-block loss ============
__global__ __launch_bounds__(128) void K4(const int* __restrict__ target,
                                          const float* __restrict__ fcb,
                                          float* __restrict__ out,
                                          float* __restrict__ ws) {
    const int tid = threadIdx.x;
    const int p = blockIdx.x * 128 + tid;
    __shared__ float sred[128];
    __shared__ int sticket;
    float lossacc = 0.f;
    {
        int i = (int)((511.0f - sqrtf((float)(261121 - 8 * p))) * 0.5f);
        while ((i + 1) * (510 - i) <= 2 * p) ++i;
        while (i > 0 && i * (511 - i) > 2 * p) --i;
        const int j = p - i * (511 - i) / 2 + i + 1;

        const float Zci  = ws[WS_ZC + i];
        const float invz = 1.f / (ws[WS_ZC + j + 1] - Zci);
        const int L = j - i + 1;
        const int* runid = (const int*)ws + WS_RUN;
        const int* stA   = (const int*)ws + WS_START;
        const int* enA   = (const int*)ws + WS_END;
        const int lbl = (runid[i] == runid[j] && stA[i] && enA[j]) ? target[j] : 0;

        const float4* pwj4 = (const float4*)(ws + WS_PW + (j + 1) * 20);
        const float4* pwi4 = (const float4*)(ws + WS_PW + i * 20);
        const float4* h14  = (const float4*)(ws + WS_HW1 + i * 20);
        const float4* h24  = (const float4*)(ws + WS_HW2 + j * 20);
        const float4* lw4  = (const float4*)(ws + WS_LW + L * 20);
        const float4* fb4  = (const float4*)fcb;
        float4* op4 = (float4*)(out + (size_t)p * 20);

        float lg[20];
        float mx = -1e30f, chosen = 0.f;
        #pragma unroll
        for (int q = 0; q < 5; q++) {
            const float4 aj = pwj4[q], ai = pwi4[q];
            const float4 bi = h14[q],  bj = h24[q];
            const float4 cl = lw4[q],  fb = fb4[q];
            float4 r;
            r.x = (aj.x - ai.x) * invz + bi.x + bj.x + cl.x + fb.x;
            r.y = (aj.y - ai.y) * invz + bi.y + bj.y + cl.y + fb.y;
            r.z = (aj.z - ai.z) * invz + bi.z + bj.z + cl.z + fb.z;
            r.w = (aj.w - ai.w) * invz + bi.w + bj.w + cl.w + fb.w;
            op4[q] = r;
            lg[q * 4 + 0] = r.x; lg[q * 4 + 1] = r.y;
            lg[q * 4 + 2] = r.z; lg[q * 4 + 3] = r.w;
            mx = fmaxf(mx, fmaxf(fmaxf(r.x, r.y), fmaxf(r.z, r.w)));
            chosen = (q * 4 + 0 == lbl) ? r.x : chosen;
            chosen = (q * 4 + 1 == lbl) ? r.y : chosen;
            chosen = (q * 4 + 2 == lbl) ? r.z : chosen;
            chosen = (q * 4 + 3 == lbl) ? r.w : chosen;
        }
        float se = 0.f;
        #pragma unroll
        for (int t = 0; t < 20; t++) se += __expf(lg[t] - mx);
        lossacc = -(chosen - mx - __logf(se));
    }
    sred[tid] = lossacc;
    __syncthreads();
    for (int off = 64; off > 0; off >>= 1) {
        if (tid < off) sred[tid] += sred[tid + off];
        __syncthreads();
    }
    if (tid == 0) ws[WS_LOSSP + blockIdx.x] = sred[0];

    __threadfence();
    __syncthreads();
    if (tid == 0) sticket = atomicAdd((int*)ws + WS_CTR2, 1);
    __syncthreads();
    if (sticket != 254) return;
    __threadfence();
    sred[tid] = ws[WS_LOSSP + tid] + ((tid < 127) ? ws[WS_LOSSP + tid + 128] : 0.f);
    __syncthreads();
    for (int off = 64; off > 0; off >>= 1) {
        if (tid < off) sred[tid] += sred[tid + off];
        __syncthreads();
    }
    if (tid == 0) out[(size_t)NPAIR * 20] = sred[0] / (float)NPAIR;
}

extern "C" void kernel_launch(void* const* d_in, const int* in_sizes, int n_in,
                              void* d_out, int out_size, void* d_ws, size_t ws_size,
                              hipStream_t stream) {
    (void)in_sizes; (void)n_in; (void)out_size; (void)ws_size;
    const float* hidden = (const float*)d_in[0];
    const int*   target = (const int*)d_in[1];
    const float* w1     = (const float*)d_in[2];
    const float* b1     = (const float*)d_in[3];
    const float* w2     = (const float*)d_in[4];
    const float* b2     = (const float*)d_in[5];
    const float* lenemb = (const float*)d_in[6];
    const float* fcw    = (const float*)d_in[7];
    const float* fcb    = (const float*)d_in[8];
    float* out = (float*)d_out;
    float* ws  = (float*)d_ws;

    K1<<<448, 256, 0, stream>>>(hidden, w1, fcw, ws);
    K2<<<256, 256, 0, stream>>>(b1, w2, ws);
    K3<<<256, 256, 0, stream>>>(b2, target, lenemb, fcw, ws);
    K4<<<255, 128, 0, stream>>>(target, fcb, out, ws);
}